// Round 6
// baseline (1543.406 us; speedup 1.0000x reference)
//
#include <hip/hip_runtime.h>
#include <stdint.h>

#define D 64
#define SCAN_CHUNK 2048   // 256 threads * 8 elements
#define BSHIFT 7          // 128 nodes per bucket

// ---------------- CSR build (two-level bucket sort) ----------------

// pass 0: bucket histogram
__global__ void bhist_kernel(const int* __restrict__ row, int* __restrict__ bcnt, int e) {
    int i = blockIdx.x * blockDim.x + threadIdx.x;
    if (i < e) atomicAdd(&bcnt[row[i] >> BSHIFT], 1);
}

// single-wave exclusive scan (carry loop supports any length)
__global__ void bscan_kernel(int* __restrict__ bsum, int nblk) {
    const int lane = threadIdx.x;   // 64 threads
    int carry = 0;
    for (int base = 0; base < nblk; base += 64) {
        int i = base + lane;
        int v = (i < nblk) ? bsum[i] : 0;
        int inc = v;
#pragma unroll
        for (int m = 1; m < 64; m <<= 1) {
            int o = __shfl_up(inc, m);
            if (lane >= m) inc += o;
        }
        if (i < nblk) bsum[i] = inc - v + carry;   // exclusive
        carry += __shfl(inc, 63);
    }
}

// pass 1: bin edges into bucket regions (sequential append per bucket)
__global__ void bucket_scatter_kernel(const int* __restrict__ row, const int* __restrict__ col,
                                      const int* __restrict__ bbase, int* __restrict__ bcursor,
                                      int* __restrict__ rbuf, int* __restrict__ cbuf, int e) {
    int i = blockIdx.x * blockDim.x + threadIdx.x;
    if (i < e) {
        int r = row[i];
        int b = r >> BSHIFT;
        int pos = bbase[b] + atomicAdd(&bcursor[b], 1);
        rbuf[pos] = r;
        cbuf[pos] = col[i];
    }
}

// degree histogram over bucket-sorted rbuf (atomics are L2-local per block)
__global__ void deg_kernel(const int* __restrict__ rbuf, int* __restrict__ deg, int e) {
    int i = blockIdx.x * blockDim.x + threadIdx.x;
    if (i < e) atomicAdd(&deg[rbuf[i]], 1);
}

__global__ __launch_bounds__(256) void blocksum_kernel(
        const int* __restrict__ deg, int* __restrict__ bsum, int n) {
    const int t = threadIdx.x;
    const int base = blockIdx.x * SCAN_CHUNK + t * 8;
    int s = 0;
#pragma unroll
    for (int j = 0; j < 8; ++j) {
        int i = base + j;
        if (i < n) s += deg[i];
    }
#pragma unroll
    for (int m = 1; m < 64; m <<= 1) s += __shfl_xor(s, m);
    __shared__ int ws[4];
    if ((t & 63) == 0) ws[t >> 6] = s;
    __syncthreads();
    if (t == 0) bsum[blockIdx.x] = ws[0] + ws[1] + ws[2] + ws[3];
}

__global__ __launch_bounds__(256) void offsets_kernel(
        const int* __restrict__ deg, const int* __restrict__ bbase,
        int* __restrict__ off, float* __restrict__ dinv, int n) {
    const int t = threadIdx.x;
    const int lane = t & 63, w = t >> 6;
    const int i0 = blockIdx.x * SCAN_CHUNK + t * 8;
    int d[8];
    int s = 0;
#pragma unroll
    for (int j = 0; j < 8; ++j) {
        int i = i0 + j;
        d[j] = (i < n) ? deg[i] : 0;
        s += d[j];
    }
    int inc = s;
#pragma unroll
    for (int m = 1; m < 64; m <<= 1) {
        int o = __shfl_up(inc, m);
        if (lane >= m) inc += o;
    }
    __shared__ int ws[4];
    if (lane == 63) ws[w] = inc;
    __syncthreads();
    int wbase = 0;
    for (int k = 0; k < w; ++k) wbase += ws[k];
    int run = bbase[blockIdx.x] + wbase + (inc - s);
#pragma unroll
    for (int j = 0; j < 8; ++j) {
        int i = i0 + j;
        if (i < n) {
            off[i] = run;
            dinv[i] = 1.0f / (float)(d[j] < 1 ? 1 : d[j]);
            run += d[j];
            if (i == n - 1) off[n] = run;
        }
    }
}

// pass 2: final placement (each block's writes confined to a ~6KB csr window)
__global__ void place_kernel(const int* __restrict__ rbuf, const int* __restrict__ cbuf,
                             const int* __restrict__ off, int* __restrict__ cursor,
                             int* __restrict__ csr, int e) {
    int i = blockIdx.x * blockDim.x + threadIdx.x;
    if (i < e) {
        int r = rbuf[i];
        int pos = off[r] + atomicAdd(&cursor[r], 1);
        csr[pos] = cbuf[i];
    }
}

// ---------------- dense GEMM: [hs | y] = x @ [Ws | Wn] ----------------
// block = 256 threads, tile = 64 nodes x 128 outputs, K = 64.
// A staged TRANSPOSED in LDS -> per-k: 2x b128 (A, broadcast) + 1x b128 (W)
// feeding 32 fmas per thread => FMA-bound, no readlane.

__global__ __launch_bounds__(256) void dense_kernel(
        const float* __restrict__ x,
        const float* __restrict__ Ws, const float* __restrict__ Wn,
        float* __restrict__ hs, float* __restrict__ y, int n, int ntiles) {
    __shared__ float Wl[D][128];      // [k][f]   32 KB
    __shared__ float At[D][68];       // [k][node] transposed, pad 68
    const int tid = threadIdx.x;
    const int mi = tid >> 5;          // 0..7 : node-octet
    const int fi = tid & 31;          // 0..31: feature quad

    for (int i = tid; i < D * 128; i += 256) {
        int k = i >> 7, f = i & 127;
        Wl[k][f] = (f < D) ? Ws[k * D + f] : Wn[k * D + (f - D)];
    }

    for (int tile = blockIdx.x; tile < ntiles; tile += gridDim.x) {
        const int base = tile * D;
#pragma unroll
        for (int ii = 0; ii < 4; ++ii) {
            int i = tid * 4 + ii * 1024;
            int node = i >> 6, k = i & 63;
            int gn = base + node; if (gn >= n) gn = n - 1;
            const float4 v = *reinterpret_cast<const float4*>(&x[(size_t)gn * D + k]);
            At[k][node] = v.x; At[k + 1][node] = v.y;
            At[k + 2][node] = v.z; At[k + 3][node] = v.w;
        }
        __syncthreads();

        float4 acc[8];
#pragma unroll
        for (int r = 0; r < 8; ++r) acc[r] = make_float4(0.f, 0.f, 0.f, 0.f);

#pragma unroll 4
        for (int k = 0; k < D; ++k) {
            const float4 w4 = *reinterpret_cast<const float4*>(&Wl[k][fi * 4]);
            float a[8];
            *reinterpret_cast<float4*>(&a[0]) =
                *reinterpret_cast<const float4*>(&At[k][mi * 8]);
            *reinterpret_cast<float4*>(&a[4]) =
                *reinterpret_cast<const float4*>(&At[k][mi * 8 + 4]);
#pragma unroll
            for (int r = 0; r < 8; ++r) {
                acc[r].x = fmaf(a[r], w4.x, acc[r].x);
                acc[r].y = fmaf(a[r], w4.y, acc[r].y);
                acc[r].z = fmaf(a[r], w4.z, acc[r].z);
                acc[r].w = fmaf(a[r], w4.w, acc[r].w);
            }
        }

#pragma unroll
        for (int r = 0; r < 8; ++r) {
            int node = base + mi * 8 + r;
            if (node < n) {
                if (fi < 16)
                    *reinterpret_cast<float4*>(&hs[(size_t)node * D + fi * 4]) = acc[r];
                else
                    *reinterpret_cast<float4*>(&y[(size_t)node * D + (fi * 4 - D)]) = acc[r];
            }
        }
        __syncthreads();
    }
}

// ---------------- gather y + bias + ReLU + LayerNorm, in-place over hs ----------------

__global__ __launch_bounds__(256, 8) void gatherln_kernel(
        const float* __restrict__ y, float* __restrict__ h_inout,
        const int* __restrict__ csr, const int* __restrict__ off,
        const float* __restrict__ dinv,
        const float* __restrict__ bs, const float* __restrict__ bn,
        const float* __restrict__ gamma, const float* __restrict__ beta, int n) {
    const int lane = threadIdx.x & 63;
    const int c16 = lane & 15;
    const int e4 = lane >> 4;
    const int wid = (blockIdx.x * blockDim.x + threadIdx.x) >> 6;
    const int nw = (gridDim.x * blockDim.x) >> 6;

    const float4 b1 = *reinterpret_cast<const float4*>(&bs[c16 * 4]);
    const float4 b2 = *reinterpret_cast<const float4*>(&bn[c16 * 4]);
    const float4 g4 = *reinterpret_cast<const float4*>(&gamma[c16 * 4]);
    const float4 t4 = *reinterpret_cast<const float4*>(&beta[c16 * 4]);
    const float bx = b1.x + b2.x, by = b1.y + b2.y;
    const float bz = b1.z + b2.z, bw = b1.w + b2.w;

    for (int node = wid; node < n; node += nw) {
        const int s = off[node];
        const int e = off[node + 1];
        float4 acc = make_float4(0.f, 0.f, 0.f, 0.f);
        for (int p = s + e4; p < e; p += 4) {
            const int c = csr[p];
            const float4 v = *reinterpret_cast<const float4*>(&y[(size_t)c * D + c16 * 4]);
            acc.x += v.x; acc.y += v.y; acc.z += v.z; acc.w += v.w;
        }
        acc.x += __shfl_xor(acc.x, 16); acc.y += __shfl_xor(acc.y, 16);
        acc.z += __shfl_xor(acc.z, 16); acc.w += __shfl_xor(acc.w, 16);
        acc.x += __shfl_xor(acc.x, 32); acc.y += __shfl_xor(acc.y, 32);
        acc.z += __shfl_xor(acc.z, 32); acc.w += __shfl_xor(acc.w, 32);

        const float di = dinv[node];
        const float4 hsv = *reinterpret_cast<const float4*>(&h_inout[(size_t)node * D + c16 * 4]);
        float hx = fmaxf(fmaf(acc.x, di, hsv.x + bx), 0.f);
        float hy = fmaxf(fmaf(acc.y, di, hsv.y + by), 0.f);
        float hz = fmaxf(fmaf(acc.z, di, hsv.z + bz), 0.f);
        float hw = fmaxf(fmaf(acc.w, di, hsv.w + bw), 0.f);

        float s1 = hx + hy + hz + hw;
        float s2 = hx * hx + hy * hy + hz * hz + hw * hw;
#pragma unroll
        for (int m = 8; m >= 1; m >>= 1) {
            s1 += __shfl_xor(s1, m);
            s2 += __shfl_xor(s2, m);
        }
        const float mu = s1 * (1.0f / 64.0f);
        const float var = s2 * (1.0f / 64.0f) - mu * mu;
        const float r = rsqrtf(var + 1e-5f);
        if (e4 == 0) {
            float4 o;
            o.x = (hx - mu) * r * g4.x + t4.x;
            o.y = (hy - mu) * r * g4.y + t4.y;
            o.z = (hz - mu) * r * g4.z + t4.z;
            o.w = (hw - mu) * r * g4.w + t4.w;
            *reinterpret_cast<float4*>(&h_inout[(size_t)node * D + c16 * 4]) = o;
        }
    }
}

// ---------------- head ----------------

__global__ __launch_bounds__(256) void head_kernel(
        const float* __restrict__ x,
        const float* __restrict__ hw1, const float* __restrict__ hb1,
        const float* __restrict__ hw2, const float* __restrict__ hb2,
        float* __restrict__ out, int n) {
    const int lane = threadIdx.x & 63;
    const int j = lane & 31;
    const int half = lane >> 5;
    const int wid = (blockIdx.x * blockDim.x + threadIdx.x) >> 6;
    const int nw = (gridDim.x * blockDim.x) >> 6;

    float w1c[32];
#pragma unroll
    for (int k = 0; k < 32; ++k) w1c[k] = hw1[(half * 32 + k) * 32 + j];
    const float b1 = hb1[j];
    const float w2 = hw2[j];
    const float b2 = hb2[0];

    for (int node = wid; node < n; node += nw) {
        float xv = x[(size_t)node * D + lane];
        float acc = 0.0f;
#pragma unroll
        for (int k = 0; k < 32; ++k) {
            float xk = __shfl(xv, half * 32 + k);
            acc = fmaf(xk, w1c[k], acc);
        }
        acc += __shfl_xor(acc, 32);
        float h1 = fmaxf(acc + b1, 0.0f);
        float p = h1 * w2;
#pragma unroll
        for (int m = 16; m >= 1; m >>= 1) p += __shfl_xor(p, m);
        if (lane == 0) out[node] = p + b2;
    }
}

// ---------------- launch ----------------

extern "C" void kernel_launch(void* const* d_in, const int* in_sizes, int n_in,
                              void* d_out, int out_size, void* d_ws, size_t ws_size,
                              hipStream_t stream) {
    const float* x     = (const float*)d_in[0];
    const int*   ei    = (const int*)d_in[1];
    const float* Ws    = (const float*)d_in[2];
    const float* bs    = (const float*)d_in[3];
    const float* Wn    = (const float*)d_in[4];
    const float* bn    = (const float*)d_in[5];
    const float* gamma = (const float*)d_in[6];
    const float* beta  = (const float*)d_in[7];
    const float* hw1   = (const float*)d_in[8];
    const float* hb1   = (const float*)d_in[9];
    const float* hw2   = (const float*)d_in[10];
    const float* hb2   = (const float*)d_in[11];

    const int N = in_sizes[0] / D;
    const int E = in_sizes[1] / 2;
    const int L = in_sizes[2] / (D * D);
    const int* row = ei;
    const int* col = ei + E;

    const int nblk = (N + SCAN_CHUNK - 1) / SCAN_CHUNK;
    const int ntiles = (N + D - 1) / D;
    const int NB = (N + (1 << BSHIFT) - 1) >> BSHIFT;   // buckets

    char* w = (char*)d_ws;
    int*   deg     = (int*)w;    w += (size_t)N * 4;
    int*   cursor  = (int*)w;    w += (size_t)N * 4;
    int*   bcnt    = (int*)w;    w += (size_t)NB * 4;
    int*   bcursor = (int*)w;    w += (size_t)NB * 4;
    int*   off     = (int*)w;    w += (size_t)(N + 1) * 4;
    float* dinv    = (float*)w;  w += (size_t)N * 4;
    int*   bsum    = (int*)w;    w += (size_t)nblk * 4;
    w = (char*)(((uintptr_t)w + 255) & ~(uintptr_t)255);
    int*   csr     = (int*)w;    w += (size_t)E * 4;
    w = (char*)(((uintptr_t)w + 255) & ~(uintptr_t)255);
    float* xb0     = (float*)w;  w += (size_t)N * D * 4;
    float* xb1     = (float*)w;  w += (size_t)N * D * 4;
    float* ybuf    = (float*)w;

    // pair buffers alias ybuf (unused until first dense_kernel): 2*E ints = 10MB <= 25.6MB
    int* rbuf = (int*)ybuf;
    int* cbuf = rbuf + E;

    // zero deg+cursor+bcnt+bcursor (contiguous)
    hipMemsetAsync(deg, 0, (size_t)(2 * N + 2 * NB) * 4, stream);

    const int eb = (E + 255) / 256;
    bhist_kernel<<<eb, 256, 0, stream>>>(row, bcnt, E);
    bscan_kernel<<<1, 64, 0, stream>>>(bcnt, NB);                       // bcnt -> bucket bases
    bucket_scatter_kernel<<<eb, 256, 0, stream>>>(row, col, bcnt, bcursor, rbuf, cbuf, E);
    deg_kernel<<<eb, 256, 0, stream>>>(rbuf, deg, E);
    blocksum_kernel<<<nblk, 256, 0, stream>>>(deg, bsum, N);
    bscan_kernel<<<1, 64, 0, stream>>>(bsum, nblk);
    offsets_kernel<<<nblk, 256, 0, stream>>>(deg, bsum, off, dinv, N);
    place_kernel<<<eb, 256, 0, stream>>>(rbuf, cbuf, off, cursor, csr, E);

    // GEMM grid: 3 tiles per block
    const int gemm_grid = (ntiles + 2) / 3;

    float* xb[2] = { xb0, xb1 };
    const float* xin = x;
    for (int l = 0; l < L; ++l) {
        float* hsb = xb[l & 1];
        dense_kernel<<<gemm_grid, 256, 0, stream>>>(xin,
            Ws + (size_t)l * D * D, Wn + (size_t)l * D * D,
            hsb, ybuf, N, ntiles);
        gatherln_kernel<<<2048, 256, 0, stream>>>(ybuf, hsb, csr, off, dinv,
            bs + (size_t)l * D, bn + (size_t)l * D,
            gamma + (size_t)l * D, beta + (size_t)l * D, N);
        xin = hsb;
    }
    head_kernel<<<2048, 256, 0, stream>>>(xin, hw1, hb1, hw2, hb2, (float*)d_out, N);
}

// Round 11
// 531.592 us; speedup vs baseline: 2.9034x; 2.9034x over previous
//
#include <hip/hip_runtime.h>
#include <stdint.h>

#define D 64
#define SCAN_CHUNK 2048   // 256 threads * 8 elements

// ---------------- CSR build ----------------

__global__ void deg_kernel(const int* __restrict__ row, int* __restrict__ deg, int e) {
    int i = blockIdx.x * blockDim.x + threadIdx.x;
    if (i < e) atomicAdd(&deg[row[i]], 1);
}

__global__ __launch_bounds__(256) void blocksum_kernel(
        const int* __restrict__ deg, int* __restrict__ bsum, int n) {
    const int t = threadIdx.x;
    const int base = blockIdx.x * SCAN_CHUNK + t * 8;
    int s = 0;
#pragma unroll
    for (int j = 0; j < 8; ++j) {
        int i = base + j;
        if (i < n) s += deg[i];
    }
#pragma unroll
    for (int m = 1; m < 64; m <<= 1) s += __shfl_xor(s, m);
    __shared__ int ws[4];
    if ((t & 63) == 0) ws[t >> 6] = s;
    __syncthreads();
    if (t == 0) bsum[blockIdx.x] = ws[0] + ws[1] + ws[2] + ws[3];
}

__global__ void bscan_kernel(int* __restrict__ bsum, int nblk) {
    const int lane = threadIdx.x;   // 64 threads
    int carry = 0;
    for (int base = 0; base < nblk; base += 64) {
        int i = base + lane;
        int v = (i < nblk) ? bsum[i] : 0;
        int inc = v;
#pragma unroll
        for (int m = 1; m < 64; m <<= 1) {
            int o = __shfl_up(inc, m);
            if (lane >= m) inc += o;
        }
        if (i < nblk) bsum[i] = inc - v + carry;   // exclusive
        carry += __shfl(inc, 63);
    }
}

__global__ __launch_bounds__(256) void offsets_kernel(
        const int* __restrict__ deg, const int* __restrict__ bbase,
        int* __restrict__ off, float* __restrict__ dinv, int n) {
    const int t = threadIdx.x;
    const int lane = t & 63, w = t >> 6;
    const int i0 = blockIdx.x * SCAN_CHUNK + t * 8;
    int d[8];
    int s = 0;
#pragma unroll
    for (int j = 0; j < 8; ++j) {
        int i = i0 + j;
        d[j] = (i < n) ? deg[i] : 0;
        s += d[j];
    }
    int inc = s;
#pragma unroll
    for (int m = 1; m < 64; m <<= 1) {
        int o = __shfl_up(inc, m);
        if (lane >= m) inc += o;
    }
    __shared__ int ws[4];
    if (lane == 63) ws[w] = inc;
    __syncthreads();
    int wbase = 0;
    for (int k = 0; k < w; ++k) wbase += ws[k];
    int run = bbase[blockIdx.x] + wbase + (inc - s);
#pragma unroll
    for (int j = 0; j < 8; ++j) {
        int i = i0 + j;
        if (i < n) {
            off[i] = run;
            dinv[i] = 1.0f / (float)(d[j] < 1 ? 1 : d[j]);
            run += d[j];
            if (i == n - 1) off[n] = run;
        }
    }
}

// direct scatter: per-node cursors (100K counters -> low contention; measured 85us)
__global__ void scatter_kernel(const int* __restrict__ row, const int* __restrict__ col,
                               const int* __restrict__ off, int* __restrict__ cursor,
                               int* __restrict__ csr, int e) {
    int i = blockIdx.x * blockDim.x + threadIdx.x;
    if (i < e) {
        int r = row[i];
        int pos = off[r] + atomicAdd(&cursor[r], 1);
        csr[pos] = col[i];
    }
}

// ---------------- dense GEMM: [hs | y] = x @ [Ws | Wn] ----------------
// block = 256 threads, tile = 64 nodes x 128 outputs, K = 64.
// A staged TRANSPOSED in LDS -> per-k: 2x b128 (A, broadcast) + 1x b128 (W)
// feeding 32 fmas per thread => FMA-bound, no readlane.

__global__ __launch_bounds__(256) void dense_kernel(
        const float* __restrict__ x,
        const float* __restrict__ Ws, const float* __restrict__ Wn,
        float* __restrict__ hs, float* __restrict__ y, int n, int ntiles) {
    __shared__ float Wl[D][128];      // [k][f]   32 KB
    __shared__ float At[D][68];       // [k][node] transposed, pad 68
    const int tid = threadIdx.x;
    const int mi = tid >> 5;          // 0..7 : node-octet
    const int fi = tid & 31;          // 0..31: feature quad

    for (int i = tid; i < D * 128; i += 256) {
        int k = i >> 7, f = i & 127;
        Wl[k][f] = (f < D) ? Ws[k * D + f] : Wn[k * D + (f - D)];
    }

    for (int tile = blockIdx.x; tile < ntiles; tile += gridDim.x) {
        const int base = tile * D;
#pragma unroll
        for (int ii = 0; ii < 4; ++ii) {
            int i = tid * 4 + ii * 1024;
            int node = i >> 6, k = i & 63;
            int gn = base + node; if (gn >= n) gn = n - 1;
            const float4 v = *reinterpret_cast<const float4*>(&x[(size_t)gn * D + k]);
            At[k][node] = v.x; At[k + 1][node] = v.y;
            At[k + 2][node] = v.z; At[k + 3][node] = v.w;
        }
        __syncthreads();

        float4 acc[8];
#pragma unroll
        for (int r = 0; r < 8; ++r) acc[r] = make_float4(0.f, 0.f, 0.f, 0.f);

#pragma unroll 4
        for (int k = 0; k < D; ++k) {
            const float4 w4 = *reinterpret_cast<const float4*>(&Wl[k][fi * 4]);
            float a[8];
            *reinterpret_cast<float4*>(&a[0]) =
                *reinterpret_cast<const float4*>(&At[k][mi * 8]);
            *reinterpret_cast<float4*>(&a[4]) =
                *reinterpret_cast<const float4*>(&At[k][mi * 8 + 4]);
#pragma unroll
            for (int r = 0; r < 8; ++r) {
                acc[r].x = fmaf(a[r], w4.x, acc[r].x);
                acc[r].y = fmaf(a[r], w4.y, acc[r].y);
                acc[r].z = fmaf(a[r], w4.z, acc[r].z);
                acc[r].w = fmaf(a[r], w4.w, acc[r].w);
            }
        }

#pragma unroll
        for (int r = 0; r < 8; ++r) {
            int node = base + mi * 8 + r;
            if (node < n) {
                if (fi < 16)
                    *reinterpret_cast<float4*>(&hs[(size_t)node * D + fi * 4]) = acc[r];
                else
                    *reinterpret_cast<float4*>(&y[(size_t)node * D + (fi * 4 - D)]) = acc[r];
            }
        }
        __syncthreads();
    }
}

// ---------------- gather y + bias + ReLU + LayerNorm, in-place over hs ----------------
// wave per node; lane = (edge-slot e4, float4-chunk c16): 4 rows per vmem instr.

__global__ __launch_bounds__(256, 8) void gatherln_kernel(
        const float* __restrict__ y, float* __restrict__ h_inout,
        const int* __restrict__ csr, const int* __restrict__ off,
        const float* __restrict__ dinv,
        const float* __restrict__ bs, const float* __restrict__ bn,
        const float* __restrict__ gamma, const float* __restrict__ beta, int n) {
    const int lane = threadIdx.x & 63;
    const int c16 = lane & 15;
    const int e4 = lane >> 4;
    const int wid = (blockIdx.x * blockDim.x + threadIdx.x) >> 6;
    const int nw = (gridDim.x * blockDim.x) >> 6;

    const float4 b1 = *reinterpret_cast<const float4*>(&bs[c16 * 4]);
    const float4 b2 = *reinterpret_cast<const float4*>(&bn[c16 * 4]);
    const float4 g4 = *reinterpret_cast<const float4*>(&gamma[c16 * 4]);
    const float4 t4 = *reinterpret_cast<const float4*>(&beta[c16 * 4]);
    const float bx = b1.x + b2.x, by = b1.y + b2.y;
    const float bz = b1.z + b2.z, bw = b1.w + b2.w;

    for (int node = wid; node < n; node += nw) {
        const int s = off[node];
        const int e = off[node + 1];
        float4 acc = make_float4(0.f, 0.f, 0.f, 0.f);
        for (int p = s + e4; p < e; p += 4) {
            const int c = csr[p];
            const float4 v = *reinterpret_cast<const float4*>(&y[(size_t)c * D + c16 * 4]);
            acc.x += v.x; acc.y += v.y; acc.z += v.z; acc.w += v.w;
        }
        acc.x += __shfl_xor(acc.x, 16); acc.y += __shfl_xor(acc.y, 16);
        acc.z += __shfl_xor(acc.z, 16); acc.w += __shfl_xor(acc.w, 16);
        acc.x += __shfl_xor(acc.x, 32); acc.y += __shfl_xor(acc.y, 32);
        acc.z += __shfl_xor(acc.z, 32); acc.w += __shfl_xor(acc.w, 32);

        const float di = dinv[node];
        const float4 hsv = *reinterpret_cast<const float4*>(&h_inout[(size_t)node * D + c16 * 4]);
        float hx = fmaxf(fmaf(acc.x, di, hsv.x + bx), 0.f);
        float hy = fmaxf(fmaf(acc.y, di, hsv.y + by), 0.f);
        float hz = fmaxf(fmaf(acc.z, di, hsv.z + bz), 0.f);
        float hw = fmaxf(fmaf(acc.w, di, hsv.w + bw), 0.f);

        float s1 = hx + hy + hz + hw;
        float s2 = hx * hx + hy * hy + hz * hz + hw * hw;
#pragma unroll
        for (int m = 8; m >= 1; m >>= 1) {
            s1 += __shfl_xor(s1, m);
            s2 += __shfl_xor(s2, m);
        }
        const float mu = s1 * (1.0f / 64.0f);
        const float var = s2 * (1.0f / 64.0f) - mu * mu;
        const float r = rsqrtf(var + 1e-5f);
        if (e4 == 0) {
            float4 o;
            o.x = (hx - mu) * r * g4.x + t4.x;
            o.y = (hy - mu) * r * g4.y + t4.y;
            o.z = (hz - mu) * r * g4.z + t4.z;
            o.w = (hw - mu) * r * g4.w + t4.w;
            *reinterpret_cast<float4*>(&h_inout[(size_t)node * D + c16 * 4]) = o;
        }
    }
}

// ---------------- head ----------------

__global__ __launch_bounds__(256) void head_kernel(
        const float* __restrict__ x,
        const float* __restrict__ hw1, const float* __restrict__ hb1,
        const float* __restrict__ hw2, const float* __restrict__ hb2,
        float* __restrict__ out, int n) {
    const int lane = threadIdx.x & 63;
    const int j = lane & 31;
    const int half = lane >> 5;
    const int wid = (blockIdx.x * blockDim.x + threadIdx.x) >> 6;
    const int nw = (gridDim.x * blockDim.x) >> 6;

    float w1c[32];
#pragma unroll
    for (int k = 0; k < 32; ++k) w1c[k] = hw1[(half * 32 + k) * 32 + j];
    const float b1 = hb1[j];
    const float w2 = hw2[j];
    const float b2 = hb2[0];

    for (int node = wid; node < n; node += nw) {
        float xv = x[(size_t)node * D + lane];
        float acc = 0.0f;
#pragma unroll
        for (int k = 0; k < 32; ++k) {
            float xk = __shfl(xv, half * 32 + k);
            acc = fmaf(xk, w1c[k], acc);
        }
        acc += __shfl_xor(acc, 32);
        float h1 = fmaxf(acc + b1, 0.0f);
        float p = h1 * w2;
#pragma unroll
        for (int m = 16; m >= 1; m >>= 1) p += __shfl_xor(p, m);
        if (lane == 0) out[node] = p + b2;
    }
}

// ---------------- launch ----------------

extern "C" void kernel_launch(void* const* d_in, const int* in_sizes, int n_in,
                              void* d_out, int out_size, void* d_ws, size_t ws_size,
                              hipStream_t stream) {
    const float* x     = (const float*)d_in[0];
    const int*   ei    = (const int*)d_in[1];
    const float* Ws    = (const float*)d_in[2];
    const float* bs    = (const float*)d_in[3];
    const float* Wn    = (const float*)d_in[4];
    const float* bn    = (const float*)d_in[5];
    const float* gamma = (const float*)d_in[6];
    const float* beta  = (const float*)d_in[7];
    const float* hw1   = (const float*)d_in[8];
    const float* hb1   = (const float*)d_in[9];
    const float* hw2   = (const float*)d_in[10];
    const float* hb2   = (const float*)d_in[11];

    const int N = in_sizes[0] / D;
    const int E = in_sizes[1] / 2;
    const int L = in_sizes[2] / (D * D);
    const int* row = ei;
    const int* col = ei + E;

    const int nblk = (N + SCAN_CHUNK - 1) / SCAN_CHUNK;
    const int ntiles = (N + D - 1) / D;

    char* w = (char*)d_ws;
    int*   deg    = (int*)w;    w += (size_t)N * 4;
    int*   cursor = (int*)w;    w += (size_t)N * 4;
    int*   off    = (int*)w;    w += (size_t)(N + 1) * 4;
    float* dinv   = (float*)w;  w += (size_t)N * 4;
    int*   bsum   = (int*)w;    w += (size_t)nblk * 4;
    w = (char*)(((uintptr_t)w + 255) & ~(uintptr_t)255);
    int*   csr    = (int*)w;    w += (size_t)E * 4;
    w = (char*)(((uintptr_t)w + 255) & ~(uintptr_t)255);
    float* xb0    = (float*)w;  w += (size_t)N * D * 4;
    float* xb1    = (float*)w;  w += (size_t)N * D * 4;
    float* ybuf   = (float*)w;

    hipMemsetAsync(deg, 0, (size_t)N * 8, stream);   // deg + cursor contiguous

    const int eb = (E + 255) / 256;
    deg_kernel<<<eb, 256, 0, stream>>>(row, deg, E);
    blocksum_kernel<<<nblk, 256, 0, stream>>>(deg, bsum, N);
    bscan_kernel<<<1, 64, 0, stream>>>(bsum, nblk);
    offsets_kernel<<<nblk, 256, 0, stream>>>(deg, bsum, off, dinv, N);
    scatter_kernel<<<eb, 256, 0, stream>>>(row, col, off, cursor, csr, E);

    // GEMM grid: 3 tiles per block
    const int gemm_grid = (ntiles + 2) / 3;

    float* xb[2] = { xb0, xb1 };
    const float* xin = x;
    for (int l = 0; l < L; ++l) {
        float* hsb = xb[l & 1];
        dense_kernel<<<gemm_grid, 256, 0, stream>>>(xin,
            Ws + (size_t)l * D * D, Wn + (size_t)l * D * D,
            hsb, ybuf, N, ntiles);
        gatherln_kernel<<<2048, 256, 0, stream>>>(ybuf, hsb, csr, off, dinv,
            bs + (size_t)l * D, bn + (size_t)l * D,
            gamma + (size_t)l * D, beta + (size_t)l * D, N);
        xin = hsb;
    }
    head_kernel<<<2048, 256, 0, stream>>>(xin, hw1, hb1, hw2, hb2, (float*)d_out, N);
}

// Round 14
// 487.889 us; speedup vs baseline: 3.1634x; 1.0896x over previous
//
#include <hip/hip_runtime.h>
#include <stdint.h>

#define D 64
#define SCAN_CHUNK 2048   // 256 threads * 8 elements

// ---------------- CSR build ----------------

// degree histogram + per-edge rank (rank = my index within my dst's bucket).
// rank write is sequential; this removes the atomic round-trip from scatter.
__global__ void deg_kernel(const int* __restrict__ row, int* __restrict__ deg,
                           int* __restrict__ rank, int e) {
    int i = blockIdx.x * blockDim.x + threadIdx.x;
    if (i < e) rank[i] = atomicAdd(&deg[row[i]], 1);
}

__global__ __launch_bounds__(256) void blocksum_kernel(
        const int* __restrict__ deg, int* __restrict__ bsum, int n) {
    const int t = threadIdx.x;
    const int base = blockIdx.x * SCAN_CHUNK + t * 8;
    int s = 0;
#pragma unroll
    for (int j = 0; j < 8; ++j) {
        int i = base + j;
        if (i < n) s += deg[i];
    }
#pragma unroll
    for (int m = 1; m < 64; m <<= 1) s += __shfl_xor(s, m);
    __shared__ int ws[4];
    if ((t & 63) == 0) ws[t >> 6] = s;
    __syncthreads();
    if (t == 0) bsum[blockIdx.x] = ws[0] + ws[1] + ws[2] + ws[3];
}

__global__ void bscan_kernel(int* __restrict__ bsum, int nblk) {
    const int lane = threadIdx.x;   // 64 threads
    int carry = 0;
    for (int base = 0; base < nblk; base += 64) {
        int i = base + lane;
        int v = (i < nblk) ? bsum[i] : 0;
        int inc = v;
#pragma unroll
        for (int m = 1; m < 64; m <<= 1) {
            int o = __shfl_up(inc, m);
            if (lane >= m) inc += o;
        }
        if (i < nblk) bsum[i] = inc - v + carry;   // exclusive
        carry += __shfl(inc, 63);
    }
}

__global__ __launch_bounds__(256) void offsets_kernel(
        const int* __restrict__ deg, const int* __restrict__ bbase,
        int* __restrict__ off, float* __restrict__ dinv, int n) {
    const int t = threadIdx.x;
    const int lane = t & 63, w = t >> 6;
    const int i0 = blockIdx.x * SCAN_CHUNK + t * 8;
    int d[8];
    int s = 0;
#pragma unroll
    for (int j = 0; j < 8; ++j) {
        int i = i0 + j;
        d[j] = (i < n) ? deg[i] : 0;
        s += d[j];
    }
    int inc = s;
#pragma unroll
    for (int m = 1; m < 64; m <<= 1) {
        int o = __shfl_up(inc, m);
        if (lane >= m) inc += o;
    }
    __shared__ int ws[4];
    if (lane == 63) ws[w] = inc;
    __syncthreads();
    int wbase = 0;
    for (int k = 0; k < w; ++k) wbase += ws[k];
    int run = bbase[blockIdx.x] + wbase + (inc - s);
#pragma unroll
    for (int j = 0; j < 8; ++j) {
        int i = i0 + j;
        if (i < n) {
            off[i] = run;
            dinv[i] = 1.0f / (float)(d[j] < 1 ? 1 : d[j]);
            run += d[j];
            if (i == n - 1) off[n] = run;
        }
    }
}

// scatter without atomics: pos = off[row] + precomputed rank.
// Chain is just load off (L2) -> independent random store; no round-trip wait.
__global__ void scatter_kernel(const int* __restrict__ row, const int* __restrict__ col,
                               const int* __restrict__ off, const int* __restrict__ rank,
                               int* __restrict__ csr, int e) {
    int i = blockIdx.x * blockDim.x + threadIdx.x;
    if (i < e) {
        csr[off[row[i]] + rank[i]] = col[i];
    }
}

// ---------------- dense GEMM: [hs | y] = x @ [Ws | Wn] ----------------
// block = 256 threads, tile = 64 nodes x 128 outputs, K = 64.
// A staged TRANSPOSED in LDS -> per-k: 2x b128 (A, broadcast) + 1x b128 (W)
// feeding 32 fmas per thread => FMA-bound, no readlane.

__global__ __launch_bounds__(256) void dense_kernel(
        const float* __restrict__ x,
        const float* __restrict__ Ws, const float* __restrict__ Wn,
        float* __restrict__ hs, float* __restrict__ y, int n, int ntiles) {
    __shared__ float Wl[D][128];      // [k][f]   32 KB
    __shared__ float At[D][68];       // [k][node] transposed, pad 68
    const int tid = threadIdx.x;
    const int mi = tid >> 5;          // 0..7 : node-octet
    const int fi = tid & 31;          // 0..31: feature quad

    for (int i = tid; i < D * 128; i += 256) {
        int k = i >> 7, f = i & 127;
        Wl[k][f] = (f < D) ? Ws[k * D + f] : Wn[k * D + (f - D)];
    }

    for (int tile = blockIdx.x; tile < ntiles; tile += gridDim.x) {
        const int base = tile * D;
#pragma unroll
        for (int ii = 0; ii < 4; ++ii) {
            int i = tid * 4 + ii * 1024;
            int node = i >> 6, k = i & 63;
            int gn = base + node; if (gn >= n) gn = n - 1;
            const float4 v = *reinterpret_cast<const float4*>(&x[(size_t)gn * D + k]);
            At[k][node] = v.x; At[k + 1][node] = v.y;
            At[k + 2][node] = v.z; At[k + 3][node] = v.w;
        }
        __syncthreads();

        float4 acc[8];
#pragma unroll
        for (int r = 0; r < 8; ++r) acc[r] = make_float4(0.f, 0.f, 0.f, 0.f);

#pragma unroll 4
        for (int k = 0; k < D; ++k) {
            const float4 w4 = *reinterpret_cast<const float4*>(&Wl[k][fi * 4]);
            float a[8];
            *reinterpret_cast<float4*>(&a[0]) =
                *reinterpret_cast<const float4*>(&At[k][mi * 8]);
            *reinterpret_cast<float4*>(&a[4]) =
                *reinterpret_cast<const float4*>(&At[k][mi * 8 + 4]);
#pragma unroll
            for (int r = 0; r < 8; ++r) {
                acc[r].x = fmaf(a[r], w4.x, acc[r].x);
                acc[r].y = fmaf(a[r], w4.y, acc[r].y);
                acc[r].z = fmaf(a[r], w4.z, acc[r].z);
                acc[r].w = fmaf(a[r], w4.w, acc[r].w);
            }
        }

#pragma unroll
        for (int r = 0; r < 8; ++r) {
            int node = base + mi * 8 + r;
            if (node < n) {
                if (fi < 16)
                    *reinterpret_cast<float4*>(&hs[(size_t)node * D + fi * 4]) = acc[r];
                else
                    *reinterpret_cast<float4*>(&y[(size_t)node * D + (fi * 4 - D)]) = acc[r];
            }
        }
        __syncthreads();
    }
}

// ---------------- gather y + bias + ReLU + LayerNorm, in-place over hs ----------------
// wave per node; lane = (edge-slot e4, float4-chunk c16): 4 rows per vmem instr.

__global__ __launch_bounds__(256, 8) void gatherln_kernel(
        const float* __restrict__ y, float* __restrict__ h_inout,
        const int* __restrict__ csr, const int* __restrict__ off,
        const float* __restrict__ dinv,
        const float* __restrict__ bs, const float* __restrict__ bn,
        const float* __restrict__ gamma, const float* __restrict__ beta, int n) {
    const int lane = threadIdx.x & 63;
    const int c16 = lane & 15;
    const int e4 = lane >> 4;
    const int wid = (blockIdx.x * blockDim.x + threadIdx.x) >> 6;
    const int nw = (gridDim.x * blockDim.x) >> 6;

    const float4 b1 = *reinterpret_cast<const float4*>(&bs[c16 * 4]);
    const float4 b2 = *reinterpret_cast<const float4*>(&bn[c16 * 4]);
    const float4 g4 = *reinterpret_cast<const float4*>(&gamma[c16 * 4]);
    const float4 t4 = *reinterpret_cast<const float4*>(&beta[c16 * 4]);
    const float bx = b1.x + b2.x, by = b1.y + b2.y;
    const float bz = b1.z + b2.z, bw = b1.w + b2.w;

    for (int node = wid; node < n; node += nw) {
        const int s = off[node];
        const int e = off[node + 1];
        float4 acc = make_float4(0.f, 0.f, 0.f, 0.f);
        for (int p = s + e4; p < e; p += 4) {
            const int c = csr[p];
            const float4 v = *reinterpret_cast<const float4*>(&y[(size_t)c * D + c16 * 4]);
            acc.x += v.x; acc.y += v.y; acc.z += v.z; acc.w += v.w;
        }
        acc.x += __shfl_xor(acc.x, 16); acc.y += __shfl_xor(acc.y, 16);
        acc.z += __shfl_xor(acc.z, 16); acc.w += __shfl_xor(acc.w, 16);
        acc.x += __shfl_xor(acc.x, 32); acc.y += __shfl_xor(acc.y, 32);
        acc.z += __shfl_xor(acc.z, 32); acc.w += __shfl_xor(acc.w, 32);

        const float di = dinv[node];
        const float4 hsv = *reinterpret_cast<const float4*>(&h_inout[(size_t)node * D + c16 * 4]);
        float hx = fmaxf(fmaf(acc.x, di, hsv.x + bx), 0.f);
        float hy = fmaxf(fmaf(acc.y, di, hsv.y + by), 0.f);
        float hz = fmaxf(fmaf(acc.z, di, hsv.z + bz), 0.f);
        float hw = fmaxf(fmaf(acc.w, di, hsv.w + bw), 0.f);

        float s1 = hx + hy + hz + hw;
        float s2 = hx * hx + hy * hy + hz * hz + hw * hw;
#pragma unroll
        for (int m = 8; m >= 1; m >>= 1) {
            s1 += __shfl_xor(s1, m);
            s2 += __shfl_xor(s2, m);
        }
        const float mu = s1 * (1.0f / 64.0f);
        const float var = s2 * (1.0f / 64.0f) - mu * mu;
        const float r = rsqrtf(var + 1e-5f);
        if (e4 == 0) {
            float4 o;
            o.x = (hx - mu) * r * g4.x + t4.x;
            o.y = (hy - mu) * r * g4.y + t4.y;
            o.z = (hz - mu) * r * g4.z + t4.z;
            o.w = (hw - mu) * r * g4.w + t4.w;
            *reinterpret_cast<float4*>(&h_inout[(size_t)node * D + c16 * 4]) = o;
        }
    }
}

// ---------------- head ----------------

__global__ __launch_bounds__(256) void head_kernel(
        const float* __restrict__ x,
        const float* __restrict__ hw1, const float* __restrict__ hb1,
        const float* __restrict__ hw2, const float* __restrict__ hb2,
        float* __restrict__ out, int n) {
    const int lane = threadIdx.x & 63;
    const int j = lane & 31;
    const int half = lane >> 5;
    const int wid = (blockIdx.x * blockDim.x + threadIdx.x) >> 6;
    const int nw = (gridDim.x * blockDim.x) >> 6;

    float w1c[32];
#pragma unroll
    for (int k = 0; k < 32; ++k) w1c[k] = hw1[(half * 32 + k) * 32 + j];
    const float b1 = hb1[j];
    const float w2 = hw2[j];
    const float b2 = hb2[0];

    for (int node = wid; node < n; node += nw) {
        float xv = x[(size_t)node * D + lane];
        float acc = 0.0f;
#pragma unroll
        for (int k = 0; k < 32; ++k) {
            float xk = __shfl(xv, half * 32 + k);
            acc = fmaf(xk, w1c[k], acc);
        }
        acc += __shfl_xor(acc, 32);
        float h1 = fmaxf(acc + b1, 0.0f);
        float p = h1 * w2;
#pragma unroll
        for (int m = 16; m >= 1; m >>= 1) p += __shfl_xor(p, m);
        if (lane == 0) out[node] = p + b2;
    }
}

// ---------------- launch ----------------

extern "C" void kernel_launch(void* const* d_in, const int* in_sizes, int n_in,
                              void* d_out, int out_size, void* d_ws, size_t ws_size,
                              hipStream_t stream) {
    const float* x     = (const float*)d_in[0];
    const int*   ei    = (const int*)d_in[1];
    const float* Ws    = (const float*)d_in[2];
    const float* bs    = (const float*)d_in[3];
    const float* Wn    = (const float*)d_in[4];
    const float* bn    = (const float*)d_in[5];
    const float* gamma = (const float*)d_in[6];
    const float* beta  = (const float*)d_in[7];
    const float* hw1   = (const float*)d_in[8];
    const float* hb1   = (const float*)d_in[9];
    const float* hw2   = (const float*)d_in[10];
    const float* hb2   = (const float*)d_in[11];

    const int N = in_sizes[0] / D;
    const int E = in_sizes[1] / 2;
    const int L = in_sizes[2] / (D * D);
    const int* row = ei;
    const int* col = ei + E;

    const int nblk = (N + SCAN_CHUNK - 1) / SCAN_CHUNK;
    const int ntiles = (N + D - 1) / D;

    char* w = (char*)d_ws;
    int*   deg    = (int*)w;    w += (size_t)N * 4;
    int*   off    = (int*)w;    w += (size_t)(N + 1) * 4;
    float* dinv   = (float*)w;  w += (size_t)N * 4;
    int*   bsum   = (int*)w;    w += (size_t)nblk * 4;
    w = (char*)(((uintptr_t)w + 255) & ~(uintptr_t)255);
    int*   rank   = (int*)w;    w += (size_t)E * 4;
    int*   csr    = (int*)w;    w += (size_t)E * 4;
    w = (char*)(((uintptr_t)w + 255) & ~(uintptr_t)255);
    float* xb0    = (float*)w;  w += (size_t)N * D * 4;
    float* xb1    = (float*)w;  w += (size_t)N * D * 4;
    float* ybuf   = (float*)w;

    hipMemsetAsync(deg, 0, (size_t)N * 4, stream);

    const int eb = (E + 255) / 256;
    deg_kernel<<<eb, 256, 0, stream>>>(row, deg, rank, E);
    blocksum_kernel<<<nblk, 256, 0, stream>>>(deg, bsum, N);
    bscan_kernel<<<1, 64, 0, stream>>>(bsum, nblk);
    offsets_kernel<<<nblk, 256, 0, stream>>>(deg, bsum, off, dinv, N);
    scatter_kernel<<<eb, 256, 0, stream>>>(row, col, off, rank, csr, E);

    // GEMM grid: 3 tiles per block
    const int gemm_grid = (ntiles + 2) / 3;

    float* xb[2] = { xb0, xb1 };
    const float* xin = x;
    for (int l = 0; l < L; ++l) {
        float* hsb = xb[l & 1];
        dense_kernel<<<gemm_grid, 256, 0, stream>>>(xin,
            Ws + (size_t)l * D * D, Wn + (size_t)l * D * D,
            hsb, ybuf, N, ntiles);
        gatherln_kernel<<<2048, 256, 0, stream>>>(ybuf, hsb, csr, off, dinv,
            bs + (size_t)l * D, bn + (size_t)l * D,
            gamma + (size_t)l * D, beta + (size_t)l * D, N);
        xin = hsb;
    }
    head_kernel<<<2048, 256, 0, stream>>>(xin, hw1, hb1, hw2, hb2, (float*)d_out, N);
}

// Round 16
// 465.150 us; speedup vs baseline: 3.3181x; 1.0489x over previous
//
#include <hip/hip_runtime.h>
#include <hip/hip_fp16.h>
#include <stdint.h>

#define D 64
#define SCAN_CHUNK 2048   // 256 threads * 8 elements

// ---------------- CSR build ----------------

// degree histogram + per-edge rank (rank = my index within my dst's bucket).
__global__ void deg_kernel(const int* __restrict__ row, int* __restrict__ deg,
                           int* __restrict__ rank, int e) {
    int i = blockIdx.x * blockDim.x + threadIdx.x;
    if (i < e) rank[i] = atomicAdd(&deg[row[i]], 1);
}

__global__ __launch_bounds__(256) void blocksum_kernel(
        const int* __restrict__ deg, int* __restrict__ bsum, int n) {
    const int t = threadIdx.x;
    const int base = blockIdx.x * SCAN_CHUNK + t * 8;
    int s = 0;
#pragma unroll
    for (int j = 0; j < 8; ++j) {
        int i = base + j;
        if (i < n) s += deg[i];
    }
#pragma unroll
    for (int m = 1; m < 64; m <<= 1) s += __shfl_xor(s, m);
    __shared__ int ws[4];
    if ((t & 63) == 0) ws[t >> 6] = s;
    __syncthreads();
    if (t == 0) bsum[blockIdx.x] = ws[0] + ws[1] + ws[2] + ws[3];
}

__global__ void bscan_kernel(int* __restrict__ bsum, int nblk) {
    const int lane = threadIdx.x;   // 64 threads
    int carry = 0;
    for (int base = 0; base < nblk; base += 64) {
        int i = base + lane;
        int v = (i < nblk) ? bsum[i] : 0;
        int inc = v;
#pragma unroll
        for (int m = 1; m < 64; m <<= 1) {
            int o = __shfl_up(inc, m);
            if (lane >= m) inc += o;
        }
        if (i < nblk) bsum[i] = inc - v + carry;   // exclusive
        carry += __shfl(inc, 63);
    }
}

__global__ __launch_bounds__(256) void offsets_kernel(
        const int* __restrict__ deg, const int* __restrict__ bbase,
        int* __restrict__ off, float* __restrict__ dinv, int n) {
    const int t = threadIdx.x;
    const int lane = t & 63, w = t >> 6;
    const int i0 = blockIdx.x * SCAN_CHUNK + t * 8;
    int d[8];
    int s = 0;
#pragma unroll
    for (int j = 0; j < 8; ++j) {
        int i = i0 + j;
        d[j] = (i < n) ? deg[i] : 0;
        s += d[j];
    }
    int inc = s;
#pragma unroll
    for (int m = 1; m < 64; m <<= 1) {
        int o = __shfl_up(inc, m);
        if (lane >= m) inc += o;
    }
    __shared__ int ws[4];
    if (lane == 63) ws[w] = inc;
    __syncthreads();
    int wbase = 0;
    for (int k = 0; k < w; ++k) wbase += ws[k];
    int run = bbase[blockIdx.x] + wbase + (inc - s);
#pragma unroll
    for (int j = 0; j < 8; ++j) {
        int i = i0 + j;
        if (i < n) {
            off[i] = run;
            dinv[i] = 1.0f / (float)(d[j] < 1 ? 1 : d[j]);
            run += d[j];
            if (i == n - 1) off[n] = run;
        }
    }
}

// scatter without atomics: pos = off[row] + precomputed rank.
__global__ void scatter_kernel(const int* __restrict__ row, const int* __restrict__ col,
                               const int* __restrict__ off, const int* __restrict__ rank,
                               int* __restrict__ csr, int e) {
    int i = blockIdx.x * blockDim.x + threadIdx.x;
    if (i < e) {
        csr[off[row[i]] + rank[i]] = col[i];
    }
}

// ---------------- dense GEMM: [hs | y] = x @ [Ws | Wn], y stored fp16 ----------------

__global__ __launch_bounds__(256) void dense_kernel(
        const float* __restrict__ x,
        const float* __restrict__ Ws, const float* __restrict__ Wn,
        float* __restrict__ hs, __half* __restrict__ yh, int n, int ntiles) {
    __shared__ float Wl[D][128];      // [k][f]   32 KB
    __shared__ float At[D][68];       // [k][node] transposed, pad 68
    const int tid = threadIdx.x;
    const int mi = tid >> 5;          // 0..7 : node-octet
    const int fi = tid & 31;          // 0..31: feature quad

    for (int i = tid; i < D * 128; i += 256) {
        int k = i >> 7, f = i & 127;
        Wl[k][f] = (f < D) ? Ws[k * D + f] : Wn[k * D + (f - D)];
    }

    for (int tile = blockIdx.x; tile < ntiles; tile += gridDim.x) {
        const int base = tile * D;
#pragma unroll
        for (int ii = 0; ii < 4; ++ii) {
            int i = tid * 4 + ii * 1024;
            int node = i >> 6, k = i & 63;
            int gn = base + node; if (gn >= n) gn = n - 1;
            const float4 v = *reinterpret_cast<const float4*>(&x[(size_t)gn * D + k]);
            At[k][node] = v.x; At[k + 1][node] = v.y;
            At[k + 2][node] = v.z; At[k + 3][node] = v.w;
        }
        __syncthreads();

        float4 acc[8];
#pragma unroll
        for (int r = 0; r < 8; ++r) acc[r] = make_float4(0.f, 0.f, 0.f, 0.f);

#pragma unroll 4
        for (int k = 0; k < D; ++k) {
            const float4 w4 = *reinterpret_cast<const float4*>(&Wl[k][fi * 4]);
            float a[8];
            *reinterpret_cast<float4*>(&a[0]) =
                *reinterpret_cast<const float4*>(&At[k][mi * 8]);
            *reinterpret_cast<float4*>(&a[4]) =
                *reinterpret_cast<const float4*>(&At[k][mi * 8 + 4]);
#pragma unroll
            for (int r = 0; r < 8; ++r) {
                acc[r].x = fmaf(a[r], w4.x, acc[r].x);
                acc[r].y = fmaf(a[r], w4.y, acc[r].y);
                acc[r].z = fmaf(a[r], w4.z, acc[r].z);
                acc[r].w = fmaf(a[r], w4.w, acc[r].w);
            }
        }

#pragma unroll
        for (int r = 0; r < 8; ++r) {
            int node = base + mi * 8 + r;
            if (node < n) {
                if (fi < 16) {
                    *reinterpret_cast<float4*>(&hs[(size_t)node * D + fi * 4]) = acc[r];
                } else {
                    union { __half2 h2[2]; uint2 u; } pk;
                    pk.h2[0] = __floats2half2_rn(acc[r].x, acc[r].y);
                    pk.h2[1] = __floats2half2_rn(acc[r].z, acc[r].w);
                    *reinterpret_cast<uint2*>(&yh[(size_t)node * D + (fi - 16) * 4]) = pk.u;
                }
            }
        }
        __syncthreads();
    }
}

// ---------------- gather y(fp16) + bias + ReLU + LayerNorm, in-place over hs ----------------
// wave per node; lane = (edge-slot e4, fp16-quad c16): 4 rows per vmem instr, 8B/lane.

__global__ __launch_bounds__(256, 8) void gatherln_kernel(
        const __half* __restrict__ yh, float* __restrict__ h_inout,
        const int* __restrict__ csr, const int* __restrict__ off,
        const float* __restrict__ dinv,
        const float* __restrict__ bs, const float* __restrict__ bn,
        const float* __restrict__ gamma, const float* __restrict__ beta, int n) {
    const int lane = threadIdx.x & 63;
    const int c16 = lane & 15;
    const int e4 = lane >> 4;
    const int wid = (blockIdx.x * blockDim.x + threadIdx.x) >> 6;
    const int nw = (gridDim.x * blockDim.x) >> 6;

    const float4 b1 = *reinterpret_cast<const float4*>(&bs[c16 * 4]);
    const float4 b2 = *reinterpret_cast<const float4*>(&bn[c16 * 4]);
    const float4 g4 = *reinterpret_cast<const float4*>(&gamma[c16 * 4]);
    const float4 t4 = *reinterpret_cast<const float4*>(&beta[c16 * 4]);
    const float bx = b1.x + b2.x, by = b1.y + b2.y;
    const float bz = b1.z + b2.z, bw = b1.w + b2.w;

    for (int node = wid; node < n; node += nw) {
        const int s = off[node];
        const int e = off[node + 1];
        float4 acc = make_float4(0.f, 0.f, 0.f, 0.f);
        for (int p = s + e4; p < e; p += 4) {
            const int c = csr[p];
            const uint2 v = *reinterpret_cast<const uint2*>(&yh[(size_t)c * D + c16 * 4]);
            const float2 f0 = __half22float2(*reinterpret_cast<const __half2*>(&v.x));
            const float2 f1 = __half22float2(*reinterpret_cast<const __half2*>(&v.y));
            acc.x += f0.x; acc.y += f0.y; acc.z += f1.x; acc.w += f1.y;
        }
        acc.x += __shfl_xor(acc.x, 16); acc.y += __shfl_xor(acc.y, 16);
        acc.z += __shfl_xor(acc.z, 16); acc.w += __shfl_xor(acc.w, 16);
        acc.x += __shfl_xor(acc.x, 32); acc.y += __shfl_xor(acc.y, 32);
        acc.z += __shfl_xor(acc.z, 32); acc.w += __shfl_xor(acc.w, 32);

        const float di = dinv[node];
        const float4 hsv = *reinterpret_cast<const float4*>(&h_inout[(size_t)node * D + c16 * 4]);
        float hx = fmaxf(fmaf(acc.x, di, hsv.x + bx), 0.f);
        float hy = fmaxf(fmaf(acc.y, di, hsv.y + by), 0.f);
        float hz = fmaxf(fmaf(acc.z, di, hsv.z + bz), 0.f);
        float hw = fmaxf(fmaf(acc.w, di, hsv.w + bw), 0.f);

        float s1 = hx + hy + hz + hw;
        float s2 = hx * hx + hy * hy + hz * hz + hw * hw;
#pragma unroll
        for (int m = 8; m >= 1; m >>= 1) {
            s1 += __shfl_xor(s1, m);
            s2 += __shfl_xor(s2, m);
        }
        const float mu = s1 * (1.0f / 64.0f);
        const float var = s2 * (1.0f / 64.0f) - mu * mu;
        const float r = rsqrtf(var + 1e-5f);
        if (e4 == 0) {
            float4 o;
            o.x = (hx - mu) * r * g4.x + t4.x;
            o.y = (hy - mu) * r * g4.y + t4.y;
            o.z = (hz - mu) * r * g4.z + t4.z;
            o.w = (hw - mu) * r * g4.w + t4.w;
            *reinterpret_cast<float4*>(&h_inout[(size_t)node * D + c16 * 4]) = o;
        }
    }
}

// ---------------- head ----------------

__global__ __launch_bounds__(256) void head_kernel(
        const float* __restrict__ x,
        const float* __restrict__ hw1, const float* __restrict__ hb1,
        const float* __restrict__ hw2, const float* __restrict__ hb2,
        float* __restrict__ out, int n) {
    const int lane = threadIdx.x & 63;
    const int j = lane & 31;
    const int half = lane >> 5;
    const int wid = (blockIdx.x * blockDim.x + threadIdx.x) >> 6;
    const int nw = (gridDim.x * blockDim.x) >> 6;

    float w1c[32];
#pragma unroll
    for (int k = 0; k < 32; ++k) w1c[k] = hw1[(half * 32 + k) * 32 + j];
    const float b1 = hb1[j];
    const float w2 = hw2[j];
    const float b2 = hb2[0];

    for (int node = wid; node < n; node += nw) {
        float xv = x[(size_t)node * D + lane];
        float acc = 0.0f;
#pragma unroll
        for (int k = 0; k < 32; ++k) {
            float xk = __shfl(xv, half * 32 + k);
            acc = fmaf(xk, w1c[k], acc);
        }
        acc += __shfl_xor(acc, 32);
        float h1 = fmaxf(acc + b1, 0.0f);
        float p = h1 * w2;
#pragma unroll
        for (int m = 16; m >= 1; m >>= 1) p += __shfl_xor(p, m);
        if (lane == 0) out[node] = p + b2;
    }
}

// ---------------- launch ----------------

extern "C" void kernel_launch(void* const* d_in, const int* in_sizes, int n_in,
                              void* d_out, int out_size, void* d_ws, size_t ws_size,
                              hipStream_t stream) {
    const float* x     = (const float*)d_in[0];
    const int*   ei    = (const int*)d_in[1];
    const float* Ws    = (const float*)d_in[2];
    const float* bs    = (const float*)d_in[3];
    const float* Wn    = (const float*)d_in[4];
    const float* bn    = (const float*)d_in[5];
    const float* gamma = (const float*)d_in[6];
    const float* beta  = (const float*)d_in[7];
    const float* hw1   = (const float*)d_in[8];
    const float* hb1   = (const float*)d_in[9];
    const float* hw2   = (const float*)d_in[10];
    const float* hb2   = (const float*)d_in[11];

    const int N = in_sizes[0] / D;
    const int E = in_sizes[1] / 2;
    const int L = in_sizes[2] / (D * D);
    const int* row = ei;
    const int* col = ei + E;

    const int nblk = (N + SCAN_CHUNK - 1) / SCAN_CHUNK;
    const int ntiles = (N + D - 1) / D;

    char* w = (char*)d_ws;
    int*   deg    = (int*)w;    w += (size_t)N * 4;
    int*   off    = (int*)w;    w += (size_t)(N + 1) * 4;
    float* dinv   = (float*)w;  w += (size_t)N * 4;
    int*   bsum   = (int*)w;    w += (size_t)nblk * 4;
    w = (char*)(((uintptr_t)w + 255) & ~(uintptr_t)255);
    int*   rank   = (int*)w;    w += (size_t)E * 4;
    int*   csr    = (int*)w;    w += (size_t)E * 4;
    w = (char*)(((uintptr_t)w + 255) & ~(uintptr_t)255);
    float* xb0    = (float*)w;  w += (size_t)N * D * 4;
    float* xb1    = (float*)w;  w += (size_t)N * D * 4;
    __half* ybuf  = (__half*)w;

    hipMemsetAsync(deg, 0, (size_t)N * 4, stream);

    const int eb = (E + 255) / 256;
    deg_kernel<<<eb, 256, 0, stream>>>(row, deg, rank, E);
    blocksum_kernel<<<nblk, 256, 0, stream>>>(deg, bsum, N);
    bscan_kernel<<<1, 64, 0, stream>>>(bsum, nblk);
    offsets_kernel<<<nblk, 256, 0, stream>>>(deg, bsum, off, dinv, N);
    scatter_kernel<<<eb, 256, 0, stream>>>(row, col, off, rank, csr, E);

    // GEMM grid: 3 tiles per block
    const int gemm_grid = (ntiles + 2) / 3;

    float* xb[2] = { xb0, xb1 };
    const float* xin = x;
    for (int l = 0; l < L; ++l) {
        float* hsb = xb[l & 1];
        dense_kernel<<<gemm_grid, 256, 0, stream>>>(xin,
            Ws + (size_t)l * D * D, Wn + (size_t)l * D * D,
            hsb, ybuf, N, ntiles);
        gatherln_kernel<<<2048, 256, 0, stream>>>(ybuf, hsb, csr, off, dinv,
            bs + (size_t)l * D, bn + (size_t)l * D,
            gamma + (size_t)l * D, beta + (size_t)l * D, N);
        xin = hsb;
    }
    head_kernel<<<2048, 256, 0, stream>>>(xin, hw1, hb1, hw2, hb2, (float*)d_out, N);
}